// Round 12
// baseline (159.330 us; speedup 1.0000x reference)
//
#include <hip/hip_runtime.h>

#define NQ    10000
#define BATCH 2
#define CDIM  256
#define DD    16
#define HH    64
#define WW    64

using bf16x8 = __attribute__((ext_vector_type(8))) short;
using f32x4  = __attribute__((ext_vector_type(4))) float;

__device__ __forceinline__ unsigned short f2bf(float f) {   // RNE f32 -> bf16
    unsigned int u = __float_as_uint(f);
    u = u + 0x7FFFu + ((u >> 16) & 1u);
    return (unsigned short)(u >> 16);
}
__device__ __forceinline__ float bf2f(unsigned short h) {
    return __uint_as_float(((unsigned int)h) << 16);
}

// ---------------- transpose (B,C,D,H,W) f32 -> (B,D,H,W,C) bf16 ----------------
__global__ __launch_bounds__(256) void k_transpose_bf16(const float* __restrict__ vol,
                                                        unsigned short* __restrict__ volt) {
    __shared__ float tile[64][65];
    int bid  = blockIdx.x;
    int cblk = bid & 3;          // C/64 = 4
    int y    = (bid >> 2) & 63;
    int z    = (bid >> 8) & 15;
    int b    = bid >> 12;
    int tid  = threadIdx.x;
    int lx   = tid & 63, wy = tid >> 6;

    const float* src = vol + (size_t)(b * CDIM + cblk * 64) * (DD * HH * WW)
                           + (size_t)z * (HH * WW) + y * WW;
#pragma unroll
    for (int i = 0; i < 16; ++i) {
        int cl = wy * 16 + i;
        tile[cl][lx] = src[(size_t)cl * (DD * HH * WW) + lx];
    }
    __syncthreads();
    unsigned int* dst32 = reinterpret_cast<unsigned int*>(
        volt + ((size_t)(b * DD + z) * HH + y) * WW * CDIM) + cblk * 32;
    int cp = tid & 31;               // channel pair
#pragma unroll
    for (int i = 0; i < 8; ++i) {
        int x = i * 8 + (tid >> 5);
        unsigned int uo = (unsigned int)f2bf(tile[cp * 2][x])
                        | ((unsigned int)f2bf(tile[cp * 2 + 1][x]) << 16);
        dst32[(size_t)x * (CDIM / 2) + cp] = uo;
    }
}

// ------------- combine: outW = A@B, outb = A@bin + badd  (256x256) -------------
template <bool BF16OUT>
__global__ __launch_bounds__(256) void k_combine(const float* __restrict__ A,
                                                 const float* __restrict__ B,
                                                 const float* __restrict__ bin,
                                                 const float* __restrict__ badd,
                                                 void* __restrict__ outW,
                                                 float* __restrict__ outb) {
    int i = blockIdx.x, j = threadIdx.x;
    __shared__ __align__(16) float row[256];
    __shared__ float red[4];
    row[j] = A[i * 256 + j];
    __syncthreads();
    float a0 = 0.f, a1 = 0.f, a2 = 0.f, a3 = 0.f;
#pragma unroll 4
    for (int k = 0; k < 256; k += 4) {
        a0 = fmaf(row[k + 0], B[(k + 0) * 256 + j], a0);
        a1 = fmaf(row[k + 1], B[(k + 1) * 256 + j], a1);
        a2 = fmaf(row[k + 2], B[(k + 2) * 256 + j], a2);
        a3 = fmaf(row[k + 3], B[(k + 3) * 256 + j], a3);
    }
    float acc = (a0 + a1) + (a2 + a3);
    if (BF16OUT)
        ((unsigned short*)outW)[i * 256 + j] = f2bf(acc);
    else
        ((float*)outW)[i * 256 + j] = acc;

    float pb = row[j] * bin[j];
    for (int off = 32; off; off >>= 1) pb += __shfl_down(pb, off, 64);
    int lane = j & 63, wv_ = j >> 6;
    if (lane == 0) red[wv_] = pb;
    __syncthreads();
    if (j == 0) outb[i] = red[0] + red[1] + red[2] + red[3] + badd[i];
}

// ---------------- spatial bucket sort of queries (256 bins) ----------------
// key = batch(1) | z-slab(4) | y-octant(3) from ref_points (offsets ignored).
__global__ __launch_bounds__(256) void k_keys(const float* __restrict__ refp,
                                              int* __restrict__ keys,
                                              int* __restrict__ hist) {
    int q = blockIdx.x * 256 + threadIdx.x;
    if (q >= BATCH * NQ) return;
    float r0 = refp[q * 3 + 0];    // -> iy
    float r2 = refp[q * 3 + 2];    // -> iz
    int iz = min(max((int)((r2 + 1.f) * 7.5f), 0), 15);
    int iy = min(max((int)((r0 + 1.f) * 31.5f), 0), 63);
    int key = (q / NQ) * 128 + iz * 8 + (iy >> 3);
    keys[q] = key;
    atomicAdd(&hist[key], 1);
}

__global__ __launch_bounds__(256) void k_scan(const int* __restrict__ hist,
                                              int* __restrict__ offs) {
    __shared__ int tmp[256];
    int t = threadIdx.x;
    int v = hist[t];
    tmp[t] = v;
    __syncthreads();
    for (int d = 1; d < 256; d <<= 1) {
        int add = (t >= d) ? tmp[t - d] : 0;
        __syncthreads();
        if (t >= d) tmp[t] += add;
        __syncthreads();
    }
    offs[t] = tmp[t] - v;   // exclusive prefix
}

__global__ __launch_bounds__(256) void k_scatter(const int* __restrict__ keys,
                                                 int* __restrict__ offs,
                                                 int* __restrict__ perm) {
    int q = blockIdx.x * 256 + threadIdx.x;
    if (q >= BATCH * NQ) return;
    int slot = atomicAdd(&offs[keys[q]], 1);
    perm[slot] = q;
}

// ---- geometry + issue 8 corner gathers for one point ----
__device__ __forceinline__ void geom_issue(
    int p, const float* __restrict__ dotsw, const float* __restrict__ bdp,
    float r0, float r1, float r2, float a,
    const ushort4* __restrict__ vb4, int lane,
    ushort4 (&u)[8], float (&wt)[8]) {
    // grid permute [1,0,2]: ix<-dim1, iy<-dim0, iz<-dim2
    float ix = fmaf(r1 + dotsw[p * 3 + 1] + bdp[p * 3 + 1], 31.5f, 31.5f);
    float iy = fmaf(r0 + dotsw[p * 3 + 0] + bdp[p * 3 + 0], 31.5f, 31.5f);
    float iz = fmaf(r2 + dotsw[p * 3 + 2] + bdp[p * 3 + 2], 7.5f, 7.5f);
    float xf = floorf(ix), yf = floorf(iy), zf = floorf(iz);
    float fx = ix - xf, fy = iy - yf, fz = iz - zf;
    int x0 = (int)xf, y0 = (int)yf, z0 = (int)zf;
    int xc[2], yc[2], zc[2];
    float wx[2], wy2[2], wz2[2];
#pragma unroll
    for (int d = 0; d < 2; ++d) {
        int xi = x0 + d, yi = y0 + d, zi = z0 + d;
        wx[d]  = (xi >= 0 && xi < WW) ? (d ? fx : 1.f - fx) : 0.f;
        wy2[d] = (yi >= 0 && yi < HH) ? (d ? fy : 1.f - fy) : 0.f;
        wz2[d] = ((zi >= 0 && zi < DD) ? (d ? fz : 1.f - fz) : 0.f) * a;
        xc[d] = min(max(xi, 0), WW - 1);
        yc[d] = min(max(yi, 0), HH - 1);
        zc[d] = min(max(zi, 0), DD - 1);
    }
    float wzy[4];
#pragma unroll
    for (int zz = 0; zz < 2; ++zz)
#pragma unroll
        for (int yy = 0; yy < 2; ++yy) wzy[zz * 2 + yy] = wz2[zz] * wy2[yy];
#pragma unroll
    for (int c = 0; c < 8; ++c) {
        int dz = c >> 2, dy = (c >> 1) & 1, dx = c & 1;
        wt[c] = wzy[dz * 2 + dy] * wx[dx];
        int off = (zc[dz] * HH + yc[dy]) * WW + xc[dx];
        off = __builtin_amdgcn_readfirstlane(off);
        u[c] = vb4[(size_t)off * (CDIM / 4) + lane];
    }
}

__device__ __forceinline__ void proc8(const ushort4 (&u)[8], const float (&wt)[8],
                                      float4& acc) {
#pragma unroll
    for (int c = 0; c < 8; ++c) {
        acc.x = fmaf(wt[c], bf2f(u[c].x), acc.x);
        acc.y = fmaf(wt[c], bf2f(u[c].y), acc.y);
        acc.z = fmaf(wt[c], bf2f(u[c].z), acc.z);
        acc.w = fmaf(wt[c], bf2f(u[c].w), acc.w);
    }
}

// ---- fused offsets + softmax + trilinear sample + attn-sum (v4 + sorted perm) ----
// Identical to the proven r4 kernel except: blocks process spatially-sorted
// queries via perm[], with XCD-chunked blockIdx swizzle (5000 % 8 == 0).
template <bool USE_VOLT>
__global__ __launch_bounds__(256) void k_sample4s(
    const float* __restrict__ query, const float* __restrict__ refp,
    const float* __restrict__ vol, const unsigned short* __restrict__ voltb,
    const float* __restrict__ Wdp, const float* __restrict__ bdp,
    const float* __restrict__ Wa, const float* __restrict__ ba,
    const int* __restrict__ perm,
    unsigned short* __restrict__ S) {
    int tid = threadIdx.x, w = tid >> 6, lane = tid & 63;
    int g = lane >> 4, ch = lane & 15;
    const int NWG = (BATCH * NQ) / 4;   // 5000
    int sbid = ((int)blockIdx.x & 7) * (NWG / 8) + ((int)blockIdx.x >> 3);
    int bq0 = sbid * 4;
    int pq[4];
#pragma unroll
    for (int q = 0; q < 4; ++q) pq[q] = perm[bq0 + q];
    __shared__ float dots[4][32];   // [query][row] (no bias)

    {
        float4 qv[4][4];
#pragma unroll
        for (int q = 0; q < 4; ++q)
#pragma unroll
            for (int i = 0; i < 4; ++i)
                qv[q][i] = *reinterpret_cast<const float4*>(
                    query + (size_t)pq[q] * 256 + ch * 16 + i * 4);
#pragma unroll
        for (int rr = 0; rr < 2; ++rr) {
            int row = w * 8 + rr * 4 + g;
            const float* rp = (row < 24) ? (Wdp + row * 256) : (Wa + (row - 24) * 256);
            float4 wv4[4];
#pragma unroll
            for (int i = 0; i < 4; ++i)
                wv4[i] = *reinterpret_cast<const float4*>(rp + ch * 16 + i * 4);
#pragma unroll
            for (int q = 0; q < 4; ++q) {
                float s = 0.f;
#pragma unroll
                for (int i = 0; i < 4; ++i)
                    s = fmaf(wv4[i].x, qv[q][i].x, fmaf(wv4[i].y, qv[q][i].y,
                        fmaf(wv4[i].z, qv[q][i].z, fmaf(wv4[i].w, qv[q][i].w, s))));
                s += __shfl_xor(s, 1); s += __shfl_xor(s, 2);
                s += __shfl_xor(s, 4); s += __shfl_xor(s, 8);
                if (ch == q) dots[q][row] = s;
            }
        }
    }
    __syncthreads();

    int bq = pq[w], b = bq / NQ;
    const float* dotsw = dots[w];
    float lg[8]; float mx = -1e30f;
#pragma unroll
    for (int p = 0; p < 8; ++p) { lg[p] = dotsw[24 + p] + ba[p]; mx = fmaxf(mx, lg[p]); }
    float se = 0.f;
#pragma unroll
    for (int p = 0; p < 8; ++p) { lg[p] = __expf(lg[p] - mx); se += lg[p]; }
    float inv = 1.f / se;
    float r0 = refp[bq * 3 + 0], r1 = refp[bq * 3 + 1], r2 = refp[bq * 3 + 2];

    float4 acc = make_float4(0.f, 0.f, 0.f, 0.f);
    if (USE_VOLT) {
        const ushort4* vb4 = reinterpret_cast<const ushort4*>(
            voltb + (size_t)b * (DD * HH * WW) * CDIM);
        ushort4 u0[8], u1[8];
        float w0a[8], w1a[8];
        geom_issue(0, dotsw, bdp, r0, r1, r2, lg[0] * inv, vb4, lane, u0, w0a);
#pragma unroll
        for (int p = 0; p < 7; ++p) {
            if ((p & 1) == 0) {
                geom_issue(p + 1, dotsw, bdp, r0, r1, r2, lg[p + 1] * inv, vb4, lane, u1, w1a);
                proc8(u0, w0a, acc);
            } else {
                geom_issue(p + 1, dotsw, bdp, r0, r1, r2, lg[p + 1] * inv, vb4, lane, u0, w0a);
                proc8(u1, w1a, acc);
            }
        }
        proc8(u1, w1a, acc);    // point 7 (issued at p==6 into u1)
    } else {
        const float* vf = vol + (size_t)b * CDIM * (DD * HH * WW);
#pragma unroll
        for (int p = 0; p < 8; ++p) {
            float a = lg[p] * inv;
            float ix = fmaf(r1 + dotsw[p * 3 + 1] + bdp[p * 3 + 1], 31.5f, 31.5f);
            float iy = fmaf(r0 + dotsw[p * 3 + 0] + bdp[p * 3 + 0], 31.5f, 31.5f);
            float iz = fmaf(r2 + dotsw[p * 3 + 2] + bdp[p * 3 + 2], 7.5f, 7.5f);
            float xf = floorf(ix), yf = floorf(iy), zf = floorf(iz);
            float fx = ix - xf, fy = iy - yf, fz = iz - zf;
            int x0 = (int)xf, y0 = (int)yf, z0 = (int)zf;
            int xc[2], yc[2], zc[2]; float wx[2], wy2[2], wz2[2];
#pragma unroll
            for (int d = 0; d < 2; ++d) {
                int xi = x0 + d, yi = y0 + d, zi = z0 + d;
                wx[d]  = (xi >= 0 && xi < WW) ? (d ? fx : 1.f - fx) : 0.f;
                wy2[d] = (yi >= 0 && yi < HH) ? (d ? fy : 1.f - fy) : 0.f;
                wz2[d] = ((zi >= 0 && zi < DD) ? (d ? fz : 1.f - fz) : 0.f) * a;
                xc[d] = min(max(xi, 0), WW - 1);
                yc[d] = min(max(yi, 0), HH - 1);
                zc[d] = min(max(zi, 0), DD - 1);
            }
#pragma unroll
            for (int c = 0; c < 8; ++c) {
                int dz = c >> 2, dy = (c >> 1) & 1, dx = c & 1;
                float wgt = wz2[dz] * wy2[dy] * wx[dx];
                int off = (zc[dz] * HH + yc[dy]) * WW + xc[dx];
#pragma unroll
                for (int cc = 0; cc < 4; ++cc) {
                    float v = vf[(size_t)(lane * 4 + cc) * (DD * HH * WW) + off];
                    (&acc.x)[cc] = fmaf(wgt, v, (&acc.x)[cc]);
                }
            }
        }
    }
    ushort4 o;
    o.x = f2bf(acc.x); o.y = f2bf(acc.y); o.z = f2bf(acc.z); o.w = f2bf(acc.w);
    reinterpret_cast<ushort4*>(S + (size_t)bq * 256)[lane] = o;
}

// ---- bf16 MFMA GEMM: out[row] = m ? S[row]@W123^T + b123 : bo ----
// BM=BN=64, BK=32, 256 thr (4 waves, each 32x32 = 2x2 frags of 16x16x32).
__global__ __launch_bounds__(256) void k_gemm_mx(
    const unsigned short* __restrict__ A,    // [M][256] bf16
    const unsigned short* __restrict__ Bw,   // [256][256] bf16 (W123[n][k])
    const float* __restrict__ bias,          // b123
    const float* __restrict__ bo,
    const int* __restrict__ mask,
    float* __restrict__ C, int M) {
    const int LDT = 40;                       // 32 + 8 pad (bf16 elems)
    __shared__ unsigned short As[64 * LDT];
    __shared__ unsigned short Bs[64 * LDT];
    int tid = threadIdx.x, wv = tid >> 6, lane = tid & 63;
    int row0 = blockIdx.x * 64, col0 = blockIdx.y * 64;
    int wr = (wv & 1) * 32, wc = (wv >> 1) * 32;
    f32x4 acc[2][2] = {};

    int sr = tid >> 2, skc = tid & 3;         // stage: row 0..63, k-chunk 0..3
    for (int k0 = 0; k0 < 256; k0 += 32) {
        int gr = row0 + sr;
        uint4 av = make_uint4(0u, 0u, 0u, 0u);
        if (gr < M)
            av = *reinterpret_cast<const uint4*>(A + (size_t)gr * 256 + k0 + skc * 8);
        *reinterpret_cast<uint4*>(&As[sr * LDT + skc * 8]) = av;
        uint4 bv = *reinterpret_cast<const uint4*>(Bw + (size_t)(col0 + sr) * 256 + k0 + skc * 8);
        *reinterpret_cast<uint4*>(&Bs[sr * LDT + skc * 8]) = bv;
        __syncthreads();
        bf16x8 af[2], bf[2];
#pragma unroll
        for (int mi = 0; mi < 2; ++mi)
            af[mi] = *reinterpret_cast<const bf16x8*>(
                &As[(wr + mi * 16 + (lane & 15)) * LDT + (lane >> 4) * 8]);
#pragma unroll
        for (int ni = 0; ni < 2; ++ni)
            bf[ni] = *reinterpret_cast<const bf16x8*>(
                &Bs[(wc + ni * 16 + (lane & 15)) * LDT + (lane >> 4) * 8]);
#pragma unroll
        for (int mi = 0; mi < 2; ++mi)
#pragma unroll
            for (int ni = 0; ni < 2; ++ni)
                acc[mi][ni] = __builtin_amdgcn_mfma_f32_16x16x32_bf16(
                    af[mi], bf[ni], acc[mi][ni], 0, 0, 0);
        __syncthreads();
    }

    int lc = lane & 15, lr4 = (lane >> 4) * 4;
    float biasv[2], bov[2];
#pragma unroll
    for (int ni = 0; ni < 2; ++ni) {
        int col = col0 + wc + ni * 16 + lc;
        biasv[ni] = bias[col];
        bov[ni]   = bo[col];
    }
#pragma unroll
    for (int mi = 0; mi < 2; ++mi)
#pragma unroll
        for (int r = 0; r < 4; ++r) {
            int row = row0 + wr + mi * 16 + lr4 + r;
            if (row >= M) continue;
            int b = row / NQ, q = row - b * NQ;
            bool mv = (mask[(b * 2 + 0) * NQ + q] | mask[(b * 2 + 1) * NQ + q]) != 0;
#pragma unroll
            for (int ni = 0; ni < 2; ++ni) {
                int col = col0 + wc + ni * 16 + lc;
                C[(size_t)row * 256 + col] = mv ? (acc[mi][ni][r] + biasv[ni]) : bov[ni];
            }
        }
}

extern "C" void kernel_launch(void* const* d_in, const int* in_sizes, int n_in,
                              void* d_out, int out_size, void* d_ws, size_t ws_size,
                              hipStream_t stream) {
    const float* query = (const float*)d_in[0];
    const float* refp  = (const float*)d_in[1];
    const float* vol   = (const float*)d_in[2];
    const int*   mask  = (const int*)d_in[3];
    const float* Wdp   = (const float*)d_in[4];
    const float* bdp   = (const float*)d_in[5];
    const float* Wa    = (const float*)d_in[6];
    const float* ba    = (const float*)d_in[7];
    const float* Wv    = (const float*)d_in[8];
    const float* bv    = (const float*)d_in[9];
    const float* Ww    = (const float*)d_in[10];
    const float* bw    = (const float*)d_in[11];
    const float* Wo    = (const float*)d_in[12];
    const float* bo    = (const float*)d_in[13];
    float* out = (float*)d_out;

    char* ws = (char*)d_ws;
    const size_t M = (size_t)BATCH * NQ;
    size_t o_S    = 0;                                   // bf16 S: M*256*2
    size_t o_W12  = o_S + M * 256 * 2;
    size_t o_b12  = o_W12 + 256 * 256 * 4;
    size_t o_W123 = o_b12 + 1024;                        // W123 bf16
    size_t o_b123 = o_W123 + 256 * 256 * 2;
    size_t o_keys = o_b123 + 1024;                       // keys: M ints
    size_t o_hist = o_keys + M * 4;
    size_t o_offs = o_hist + 1024;
    size_t o_perm = o_offs + 1024;
    size_t o_volt = (o_perm + M * 4 + 255) & ~(size_t)255;
    size_t need_volt = o_volt + (size_t)BATCH * DD * HH * WW * CDIM * 2;
    bool use_volt = ws_size >= need_volt;

    unsigned short* Sb   = (unsigned short*)(ws + o_S);
    float*          W12  = (float*)(ws + o_W12);
    float*          b12  = (float*)(ws + o_b12);
    unsigned short* W123 = (unsigned short*)(ws + o_W123);
    float*          b123 = (float*)(ws + o_b123);
    int*            keys = (int*)(ws + o_keys);
    int*            hist = (int*)(ws + o_hist);
    int*            offs = (int*)(ws + o_offs);
    int*            perm = (int*)(ws + o_perm);
    unsigned short* volt = (unsigned short*)(ws + o_volt);

    // spatial bucket sort of queries (deterministic output: per-query work
    // is independent; perm only reorders which block computes which query)
    hipMemsetAsync(hist, 0, 1024, stream);
    int nqb = (int)((M + 255) / 256);
    k_keys<<<nqb, 256, 0, stream>>>(refp, keys, hist);
    k_scan<<<1, 256, 0, stream>>>(hist, offs);
    k_scatter<<<nqb, 256, 0, stream>>>(keys, offs, perm);

    if (use_volt)
        k_transpose_bf16<<<BATCH * DD * HH * (CDIM / 64), 256, 0, stream>>>(vol, volt);
    k_combine<false><<<256, 256, 0, stream>>>(Ww, Wv, bv, bw, W12, b12);
    k_combine<true ><<<256, 256, 0, stream>>>(Wo, W12, b12, bo, W123, b123);

    if (use_volt)
        k_sample4s<true><<<(int)(M / 4), 256, 0, stream>>>(query, refp, vol, volt,
                                                           Wdp, bdp, Wa, ba, perm, Sb);
    else
        k_sample4s<false><<<(int)(M / 4), 256, 0, stream>>>(query, refp, vol, volt,
                                                            Wdp, bdp, Wa, ba, perm, Sb);

    dim3 g((unsigned)((M + 63) / 64), 4);
    k_gemm_mx<<<g, 256, 0, stream>>>(Sb, W123, b123, bo, mask, out, (int)M);
}

// Round 14
// 133.465 us; speedup vs baseline: 1.1938x; 1.1938x over previous
//
#include <hip/hip_runtime.h>

#define NQ    10000
#define BATCH 2
#define CDIM  256
#define DD    16
#define HH    64
#define WW    64

using bf16x8 = __attribute__((ext_vector_type(8))) short;
using f32x4  = __attribute__((ext_vector_type(4))) float;

__device__ __forceinline__ unsigned short f2bf(float f) {   // RNE f32 -> bf16
    unsigned int u = __float_as_uint(f);
    u = u + 0x7FFFu + ((u >> 16) & 1u);
    return (unsigned short)(u >> 16);
}
__device__ __forceinline__ float bf2f(unsigned short h) {
    return __uint_as_float(((unsigned int)h) << 16);
}

// ---------------- transpose (B,C,D,H,W) f32 -> (B,D,H,W,C) bf16 ----------------
__global__ __launch_bounds__(256) void k_transpose_bf16(const float* __restrict__ vol,
                                                        unsigned short* __restrict__ volt) {
    __shared__ float tile[64][65];
    int bid  = blockIdx.x;
    int cblk = bid & 3;          // C/64 = 4
    int y    = (bid >> 2) & 63;
    int z    = (bid >> 8) & 15;
    int b    = bid >> 12;
    int tid  = threadIdx.x;
    int lx   = tid & 63, wy = tid >> 6;

    const float* src = vol + (size_t)(b * CDIM + cblk * 64) * (DD * HH * WW)
                           + (size_t)z * (HH * WW) + y * WW;
#pragma unroll
    for (int i = 0; i < 16; ++i) {
        int cl = wy * 16 + i;
        tile[cl][lx] = src[(size_t)cl * (DD * HH * WW) + lx];
    }
    __syncthreads();
    unsigned int* dst32 = reinterpret_cast<unsigned int*>(
        volt + ((size_t)(b * DD + z) * HH + y) * WW * CDIM) + cblk * 32;
    int cp = tid & 31;               // channel pair
#pragma unroll
    for (int i = 0; i < 8; ++i) {
        int x = i * 8 + (tid >> 5);
        unsigned int uo = (unsigned int)f2bf(tile[cp * 2][x])
                        | ((unsigned int)f2bf(tile[cp * 2 + 1][x]) << 16);
        dst32[(size_t)x * (CDIM / 2) + cp] = uo;
    }
}

// ------------- combine: outW = A@B, outb = A@bin + badd  (256x256) -------------
template <bool BF16OUT>
__global__ __launch_bounds__(256) void k_combine(const float* __restrict__ A,
                                                 const float* __restrict__ B,
                                                 const float* __restrict__ bin,
                                                 const float* __restrict__ badd,
                                                 void* __restrict__ outW,
                                                 float* __restrict__ outb) {
    int i = blockIdx.x, j = threadIdx.x;
    __shared__ __align__(16) float row[256];
    __shared__ float red[4];
    row[j] = A[i * 256 + j];
    __syncthreads();
    float a0 = 0.f, a1 = 0.f, a2 = 0.f, a3 = 0.f;
#pragma unroll 4
    for (int k = 0; k < 256; k += 4) {
        a0 = fmaf(row[k + 0], B[(k + 0) * 256 + j], a0);
        a1 = fmaf(row[k + 1], B[(k + 1) * 256 + j], a1);
        a2 = fmaf(row[k + 2], B[(k + 2) * 256 + j], a2);
        a3 = fmaf(row[k + 3], B[(k + 3) * 256 + j], a3);
    }
    float acc = (a0 + a1) + (a2 + a3);
    if (BF16OUT)
        ((unsigned short*)outW)[i * 256 + j] = f2bf(acc);
    else
        ((float*)outW)[i * 256 + j] = acc;

    float pb = row[j] * bin[j];
    for (int off = 32; off; off >>= 1) pb += __shfl_down(pb, off, 64);
    int lane = j & 63, wv_ = j >> 6;
    if (lane == 0) red[wv_] = pb;
    __syncthreads();
    if (j == 0) outb[i] = red[0] + red[1] + red[2] + red[3] + badd[i];
}

// ---- geometry + issue 8 corner gathers for one point ----
__device__ __forceinline__ void geom_issue(
    int p, const float* __restrict__ dotsw, const float* __restrict__ bdp,
    float r0, float r1, float r2, float a,
    const ushort4* __restrict__ vb4, int lane,
    ushort4 (&u)[8], float (&wt)[8]) {
    // grid permute [1,0,2]: ix<-dim1, iy<-dim0, iz<-dim2
    float ix = fmaf(r1 + dotsw[p * 3 + 1] + bdp[p * 3 + 1], 31.5f, 31.5f);
    float iy = fmaf(r0 + dotsw[p * 3 + 0] + bdp[p * 3 + 0], 31.5f, 31.5f);
    float iz = fmaf(r2 + dotsw[p * 3 + 2] + bdp[p * 3 + 2], 7.5f, 7.5f);
    float xf = floorf(ix), yf = floorf(iy), zf = floorf(iz);
    float fx = ix - xf, fy = iy - yf, fz = iz - zf;
    int x0 = (int)xf, y0 = (int)yf, z0 = (int)zf;
    int xc[2], yc[2], zc[2];
    float wx[2], wy2[2], wz2[2];
#pragma unroll
    for (int d = 0; d < 2; ++d) {
        int xi = x0 + d, yi = y0 + d, zi = z0 + d;
        wx[d]  = (xi >= 0 && xi < WW) ? (d ? fx : 1.f - fx) : 0.f;
        wy2[d] = (yi >= 0 && yi < HH) ? (d ? fy : 1.f - fy) : 0.f;
        wz2[d] = ((zi >= 0 && zi < DD) ? (d ? fz : 1.f - fz) : 0.f) * a;
        xc[d] = min(max(xi, 0), WW - 1);
        yc[d] = min(max(yi, 0), HH - 1);
        zc[d] = min(max(zi, 0), DD - 1);
    }
    float wzy[4];
#pragma unroll
    for (int zz = 0; zz < 2; ++zz)
#pragma unroll
        for (int yy = 0; yy < 2; ++yy) wzy[zz * 2 + yy] = wz2[zz] * wy2[yy];
#pragma unroll
    for (int c = 0; c < 8; ++c) {
        int dz = c >> 2, dy = (c >> 1) & 1, dx = c & 1;
        wt[c] = wzy[dz * 2 + dy] * wx[dx];
        int off = (zc[dz] * HH + yc[dy]) * WW + xc[dx];
        off = __builtin_amdgcn_readfirstlane(off);
        u[c] = vb4[(size_t)off * (CDIM / 4) + lane];
    }
}

__device__ __forceinline__ void proc8(const ushort4 (&u)[8], const float (&wt)[8],
                                      float4& acc) {
#pragma unroll
    for (int c = 0; c < 8; ++c) {
        acc.x = fmaf(wt[c], bf2f(u[c].x), acc.x);
        acc.y = fmaf(wt[c], bf2f(u[c].y), acc.y);
        acc.z = fmaf(wt[c], bf2f(u[c].z), acc.z);
        acc.w = fmaf(wt[c], bf2f(u[c].w), acc.w);
    }
}

// ---- fused offsets + softmax + trilinear sample + attn-sum (v4, S -> bf16) ----
// Block = 4 queries (4 waves); wave w owns query bq0+w. 2-deep pipelined corner
// gathers (16 dwordx4 in flight). S written as bf16 for the MFMA GEMM.
template <bool USE_VOLT>
__global__ __launch_bounds__(256) void k_sample4(
    const float* __restrict__ query, const float* __restrict__ refp,
    const float* __restrict__ vol, const unsigned short* __restrict__ voltb,
    const float* __restrict__ Wdp, const float* __restrict__ bdp,
    const float* __restrict__ Wa, const float* __restrict__ ba,
    unsigned short* __restrict__ S) {
    int tid = threadIdx.x, w = tid >> 6, lane = tid & 63;
    int g = lane >> 4, ch = lane & 15;
    int bq0 = blockIdx.x * 4;
    __shared__ float dots[4][32];   // [query][row] (no bias)

    {
        float4 qv[4][4];
#pragma unroll
        for (int q = 0; q < 4; ++q)
#pragma unroll
            for (int i = 0; i < 4; ++i)
                qv[q][i] = *reinterpret_cast<const float4*>(
                    query + (size_t)(bq0 + q) * 256 + ch * 16 + i * 4);
#pragma unroll
        for (int rr = 0; rr < 2; ++rr) {
            int row = w * 8 + rr * 4 + g;
            const float* rp = (row < 24) ? (Wdp + row * 256) : (Wa + (row - 24) * 256);
            float4 wv4[4];
#pragma unroll
            for (int i = 0; i < 4; ++i)
                wv4[i] = *reinterpret_cast<const float4*>(rp + ch * 16 + i * 4);
#pragma unroll
            for (int q = 0; q < 4; ++q) {
                float s = 0.f;
#pragma unroll
                for (int i = 0; i < 4; ++i)
                    s = fmaf(wv4[i].x, qv[q][i].x, fmaf(wv4[i].y, qv[q][i].y,
                        fmaf(wv4[i].z, qv[q][i].z, fmaf(wv4[i].w, qv[q][i].w, s))));
                s += __shfl_xor(s, 1); s += __shfl_xor(s, 2);
                s += __shfl_xor(s, 4); s += __shfl_xor(s, 8);
                if (ch == q) dots[q][row] = s;
            }
        }
    }
    __syncthreads();

    int bq = bq0 + w, b = bq / NQ;
    const float* dotsw = dots[w];
    float lg[8]; float mx = -1e30f;
#pragma unroll
    for (int p = 0; p < 8; ++p) { lg[p] = dotsw[24 + p] + ba[p]; mx = fmaxf(mx, lg[p]); }
    float se = 0.f;
#pragma unroll
    for (int p = 0; p < 8; ++p) { lg[p] = __expf(lg[p] - mx); se += lg[p]; }
    float inv = 1.f / se;
    float r0 = refp[bq * 3 + 0], r1 = refp[bq * 3 + 1], r2 = refp[bq * 3 + 2];

    float4 acc = make_float4(0.f, 0.f, 0.f, 0.f);
    if (USE_VOLT) {
        const ushort4* vb4 = reinterpret_cast<const ushort4*>(
            voltb + (size_t)b * (DD * HH * WW) * CDIM);
        ushort4 u0[8], u1[8];
        float w0a[8], w1a[8];
        geom_issue(0, dotsw, bdp, r0, r1, r2, lg[0] * inv, vb4, lane, u0, w0a);
#pragma unroll
        for (int p = 0; p < 7; ++p) {
            if ((p & 1) == 0) {
                geom_issue(p + 1, dotsw, bdp, r0, r1, r2, lg[p + 1] * inv, vb4, lane, u1, w1a);
                proc8(u0, w0a, acc);
            } else {
                geom_issue(p + 1, dotsw, bdp, r0, r1, r2, lg[p + 1] * inv, vb4, lane, u0, w0a);
                proc8(u1, w1a, acc);
            }
        }
        proc8(u1, w1a, acc);    // point 7 (issued at p==6 into u1)
    } else {
        const float* vf = vol + (size_t)b * CDIM * (DD * HH * WW);
#pragma unroll
        for (int p = 0; p < 8; ++p) {
            float a = lg[p] * inv;
            float ix = fmaf(r1 + dotsw[p * 3 + 1] + bdp[p * 3 + 1], 31.5f, 31.5f);
            float iy = fmaf(r0 + dotsw[p * 3 + 0] + bdp[p * 3 + 0], 31.5f, 31.5f);
            float iz = fmaf(r2 + dotsw[p * 3 + 2] + bdp[p * 3 + 2], 7.5f, 7.5f);
            float xf = floorf(ix), yf = floorf(iy), zf = floorf(iz);
            float fx = ix - xf, fy = iy - yf, fz = iz - zf;
            int x0 = (int)xf, y0 = (int)yf, z0 = (int)zf;
            int xc[2], yc[2], zc[2]; float wx[2], wy2[2], wz2[2];
#pragma unroll
            for (int d = 0; d < 2; ++d) {
                int xi = x0 + d, yi = y0 + d, zi = z0 + d;
                wx[d]  = (xi >= 0 && xi < WW) ? (d ? fx : 1.f - fx) : 0.f;
                wy2[d] = (yi >= 0 && yi < HH) ? (d ? fy : 1.f - fy) : 0.f;
                wz2[d] = ((zi >= 0 && zi < DD) ? (d ? fz : 1.f - fz) : 0.f) * a;
                xc[d] = min(max(xi, 0), WW - 1);
                yc[d] = min(max(yi, 0), HH - 1);
                zc[d] = min(max(zi, 0), DD - 1);
            }
#pragma unroll
            for (int c = 0; c < 8; ++c) {
                int dz = c >> 2, dy = (c >> 1) & 1, dx = c & 1;
                float wgt = wz2[dz] * wy2[dy] * wx[dx];
                int off = (zc[dz] * HH + yc[dy]) * WW + xc[dx];
#pragma unroll
                for (int cc = 0; cc < 4; ++cc) {
                    float v = vf[(size_t)(lane * 4 + cc) * (DD * HH * WW) + off];
                    (&acc.x)[cc] = fmaf(wgt, v, (&acc.x)[cc]);
                }
            }
        }
    }
    ushort4 o;
    o.x = f2bf(acc.x); o.y = f2bf(acc.y); o.z = f2bf(acc.z); o.w = f2bf(acc.w);
    reinterpret_cast<ushort4*>(S + (size_t)bq * 256)[lane] = o;
}

// ---- bf16 MFMA GEMM: out[row] = m ? S[row]@W123^T + b123 : bo ----
// BM=BN=64, BK=32, 256 thr (4 waves, each 32x32 = 2x2 frags of 16x16x32).
__global__ __launch_bounds__(256) void k_gemm_mx(
    const unsigned short* __restrict__ A,    // [M][256] bf16
    const unsigned short* __restrict__ Bw,   // [256][256] bf16 (W123[n][k])
    const float* __restrict__ bias,          // b123
    const float* __restrict__ bo,
    const int* __restrict__ mask,
    float* __restrict__ C, int M) {
    const int LDT = 40;                       // 32 + 8 pad (bf16 elems)
    __shared__ unsigned short As[64 * LDT];
    __shared__ unsigned short Bs[64 * LDT];
    int tid = threadIdx.x, wv = tid >> 6, lane = tid & 63;
    int row0 = blockIdx.x * 64, col0 = blockIdx.y * 64;
    int wr = (wv & 1) * 32, wc = (wv >> 1) * 32;
    f32x4 acc[2][2] = {};

    int sr = tid >> 2, skc = tid & 3;         // stage: row 0..63, k-chunk 0..3
    for (int k0 = 0; k0 < 256; k0 += 32) {
        int gr = row0 + sr;
        uint4 av = make_uint4(0u, 0u, 0u, 0u);
        if (gr < M)
            av = *reinterpret_cast<const uint4*>(A + (size_t)gr * 256 + k0 + skc * 8);
        *reinterpret_cast<uint4*>(&As[sr * LDT + skc * 8]) = av;
        uint4 bv = *reinterpret_cast<const uint4*>(Bw + (size_t)(col0 + sr) * 256 + k0 + skc * 8);
        *reinterpret_cast<uint4*>(&Bs[sr * LDT + skc * 8]) = bv;
        __syncthreads();
        bf16x8 af[2], bf[2];
#pragma unroll
        for (int mi = 0; mi < 2; ++mi)
            af[mi] = *reinterpret_cast<const bf16x8*>(
                &As[(wr + mi * 16 + (lane & 15)) * LDT + (lane >> 4) * 8]);
#pragma unroll
        for (int ni = 0; ni < 2; ++ni)
            bf[ni] = *reinterpret_cast<const bf16x8*>(
                &Bs[(wc + ni * 16 + (lane & 15)) * LDT + (lane >> 4) * 8]);
#pragma unroll
        for (int mi = 0; mi < 2; ++mi)
#pragma unroll
            for (int ni = 0; ni < 2; ++ni)
                acc[mi][ni] = __builtin_amdgcn_mfma_f32_16x16x32_bf16(
                    af[mi], bf[ni], acc[mi][ni], 0, 0, 0);
        __syncthreads();
    }

    int lc = lane & 15, lr4 = (lane >> 4) * 4;
    float biasv[2], bov[2];
#pragma unroll
    for (int ni = 0; ni < 2; ++ni) {
        int col = col0 + wc + ni * 16 + lc;
        biasv[ni] = bias[col];
        bov[ni]   = bo[col];
    }
#pragma unroll
    for (int mi = 0; mi < 2; ++mi)
#pragma unroll
        for (int r = 0; r < 4; ++r) {
            int row = row0 + wr + mi * 16 + lr4 + r;
            if (row >= M) continue;
            int b = row / NQ, q = row - b * NQ;
            bool mv = (mask[(b * 2 + 0) * NQ + q] | mask[(b * 2 + 1) * NQ + q]) != 0;
#pragma unroll
            for (int ni = 0; ni < 2; ++ni) {
                int col = col0 + wc + ni * 16 + lc;
                C[(size_t)row * 256 + col] = mv ? (acc[mi][ni][r] + biasv[ni]) : bov[ni];
            }
        }
}

extern "C" void kernel_launch(void* const* d_in, const int* in_sizes, int n_in,
                              void* d_out, int out_size, void* d_ws, size_t ws_size,
                              hipStream_t stream) {
    const float* query = (const float*)d_in[0];
    const float* refp  = (const float*)d_in[1];
    const float* vol   = (const float*)d_in[2];
    const int*   mask  = (const int*)d_in[3];
    const float* Wdp   = (const float*)d_in[4];
    const float* bdp   = (const float*)d_in[5];
    const float* Wa    = (const float*)d_in[6];
    const float* ba    = (const float*)d_in[7];
    const float* Wv    = (const float*)d_in[8];
    const float* bv    = (const float*)d_in[9];
    const float* Ww    = (const float*)d_in[10];
    const float* bw    = (const float*)d_in[11];
    const float* Wo    = (const float*)d_in[12];
    const float* bo    = (const float*)d_in[13];
    float* out = (float*)d_out;

    char* ws = (char*)d_ws;
    const size_t M = (size_t)BATCH * NQ;
    size_t o_S    = 0;                                   // bf16 S: M*256*2
    size_t o_W12  = o_S + M * 256 * 2;
    size_t o_b12  = o_W12 + 256 * 256 * 4;
    size_t o_W123 = o_b12 + 1024;                        // W123 bf16
    size_t o_b123 = o_W123 + 256 * 256 * 2;
    size_t o_volt = (o_b123 + 1024 + 255) & ~(size_t)255;
    size_t need_volt = o_volt + (size_t)BATCH * DD * HH * WW * CDIM * 2;
    bool use_volt = ws_size >= need_volt;

    unsigned short* Sb   = (unsigned short*)(ws + o_S);
    float*          W12  = (float*)(ws + o_W12);
    float*          b12  = (float*)(ws + o_b12);
    unsigned short* W123 = (unsigned short*)(ws + o_W123);
    float*          b123 = (float*)(ws + o_b123);
    unsigned short* volt = (unsigned short*)(ws + o_volt);

    if (use_volt)
        k_transpose_bf16<<<BATCH * DD * HH * (CDIM / 64), 256, 0, stream>>>(vol, volt);
    k_combine<false><<<256, 256, 0, stream>>>(Ww, Wv, bv, bw, W12, b12);
    k_combine<true ><<<256, 256, 0, stream>>>(Wo, W12, b12, bo, W123, b123);

    if (use_volt)
        k_sample4<true><<<(int)(M / 4), 256, 0, stream>>>(query, refp, vol, volt,
                                                          Wdp, bdp, Wa, ba, Sb);
    else
        k_sample4<false><<<(int)(M / 4), 256, 0, stream>>>(query, refp, vol, volt,
                                                           Wdp, bdp, Wa, ba, Sb);

    dim3 g((unsigned)((M + 63) / 64), 4);
    k_gemm_mx<<<g, 256, 0, stream>>>(Sb, W123, b123, bo, mask, out, (int)M);
}